// Round 1
// baseline (72.512 us; speedup 1.0000x reference)
//
#include <hip/hip_runtime.h>

// ToroidalSOM distance kernel: out[b][n] = ||w_n - x_b||^2
//   = ||w_n||^2 + ||x_b||^2 - 2 * dot(w_n, x_b)
// B=128, D=64, N=R*C=16384. fp32 throughout.
//
// v2: x read through the SCALAR path (uniform address -> s_load, scalar cache),
// so the inner loop is pure v_fmac(vdst, s_x, v_w) with NO per-batch LDS reads
// (v1 issued 256 ds_read_b128 per wave -> LDS-issue bound at ~27 us).
// BT dropped 16->8: grid (64,16) = 1024 blocks = 4 blocks/CU = 4 waves/SIMD
// for latency hiding (v1 was grid-limited to 2 waves/SIMD).
// LDS now only a 32 B ||x||^2 broadcast buffer.

#define SOM_B   128
#define SOM_D   64
#define SOM_N   16384   // 128*128 neurons
#define SOM_BT  8       // batches per block
#define SOM_TPB 256

__global__ __launch_bounds__(SOM_TPB, 4)
void som_dist_kernel(const float* __restrict__ x,
                     const float* __restrict__ w,
                     float* __restrict__ out) {
    __shared__ float x2s[SOM_BT];   // per-batch ||x||^2 (32 B)

    const int tid = threadIdx.x;
    const int n   = blockIdx.x * SOM_TPB + tid;   // neuron index
    const int b0  = blockIdx.y * SOM_BT;          // first batch of this tile

    // Per-batch ||x||^2 (8 threads; x is 32 KB total, L1/L2-hot)
    if (tid < SOM_BT) {
        const float4* xr = (const float4*)(x + (size_t)(b0 + tid) * SOM_D);
        float s = 0.f;
        #pragma unroll
        for (int i = 0; i < 16; ++i) {
            float4 v = xr[i];
            s += v.x * v.x + v.y * v.y + v.z * v.z + v.w * v.w;
        }
        x2s[tid] = s;
    }

    // This neuron's weight vector into registers (16 x float4 = 64 VGPRs)
    float4 wr[16];
    {
        const float4* wg = (const float4*)(w + (size_t)n * SOM_D);
        #pragma unroll
        for (int i = 0; i < 16; ++i) wr[i] = wg[i];
    }
    float wn2 = 0.f;
    #pragma unroll
    for (int i = 0; i < 16; ++i) {
        wn2 += wr[i].x * wr[i].x + wr[i].y * wr[i].y
             + wr[i].z * wr[i].z + wr[i].w * wr[i].w;
    }

    __syncthreads();  // x2s visible

    // 8 independent 64-FMA chains; x loads are wave-uniform -> s_load + SGPR
    // operand in v_fmac (1 SGPR read per VALU inst, legal).
    #pragma unroll
    for (int b = 0; b < SOM_BT; ++b) {
        const float* __restrict__ xb = x + (size_t)(b0 + b) * SOM_D;  // uniform
        float acc = 0.f;
        #pragma unroll
        for (int i = 0; i < 16; ++i) {
            acc += wr[i].x * xb[4 * i + 0] + wr[i].y * xb[4 * i + 1]
                 + wr[i].z * xb[4 * i + 2] + wr[i].w * xb[4 * i + 3];
        }
        // res = wn2 + x2 - 2*acc, fused
        out[(size_t)(b0 + b) * SOM_N + n] =
            __builtin_fmaf(-2.f, acc, wn2 + x2s[b]);   // coalesced store
    }
}

extern "C" void kernel_launch(void* const* d_in, const int* in_sizes, int n_in,
                              void* d_out, int out_size, void* d_ws, size_t ws_size,
                              hipStream_t stream) {
    const float* x = (const float*)d_in[0];   // (128, 64)
    const float* w = (const float*)d_in[1];   // (128, 128, 64)
    float* out = (float*)d_out;               // (128, 128, 128)

    dim3 grid(SOM_N / SOM_TPB, SOM_B / SOM_BT);   // (64, 16)
    dim3 block(SOM_TPB);
    som_dist_kernel<<<grid, block, 0, stream>>>(x, w, out);
}

// Round 2
// 67.789 us; speedup vs baseline: 1.0697x; 1.0697x over previous
//
#include <hip/hip_runtime.h>

// ToroidalSOM distance kernel v3: out[b][n] = ||w_n||^2 + ||x_b||^2 - 2*dot(w_n,x_b)
// B=128, D=64, N=16384.
//
// The -2*dot term is a GEMM (M=128, N=16384, K=64) -> computed on the matrix
// cores with split-precision bf16 (Markidis 3-pass):
//   f = hi + lo,  hi = bf16_rn(f), lo = bf16_rn(f - hi)
//   dot ~= Ah*Bh + Al*Bh + Ah*Bl      (dropped Al*Bl ~ 2^-16 relative)
// Norms ||w||^2, ||x||^2 computed exactly in fp32 (VALU pre-pass -> LDS).
//
// mfma_f32_16x16x32_bf16 fragment mapping (HW-verified m89/m91):
//   A: lane&15 = row(m),  k = (lane>>4)*8 + j   (j = elem 0..7)
//   B: lane&15 = col(n),  same k mapping (A/B symmetric; any consistent
//      k-permutation cancels in the contraction)
//   D: col = lane&15, row = (lane>>4)*4 + reg
//
// Tiling: block = 256 thr (4 waves), covers 64 n-cols x 32 b-rows.
//   wave wv -> 16 n-cols, 2 b-subtiles of 16, K=64 = 2 ksteps of 32.
//   12 MFMAs/wave. Grid (256, 4) = 1024 blocks = 4 blocks/CU = 4 waves/SIMD.
//   Same-x blocks are 256 apart in linear id (256%8==0) -> same XCD -> w slice
//   stays L2-local across the 4 b-quarter blocks.

#define SOM_B   128
#define SOM_D   64
#define SOM_N   16384
#define SOM_TPB 256
#define BLK_N   64
#define BLK_BQ  32

typedef __bf16 bf16x8 __attribute__((ext_vector_type(8)));
typedef float  f32x4  __attribute__((ext_vector_type(4)));

// split 8 fp32 (two float4) into hi/lo bf16x8 fragments
__device__ __forceinline__ void split8(float4 f0, float4 f1,
                                       bf16x8* hi, bf16x8* lo) {
    float f[8] = {f0.x, f0.y, f0.z, f0.w, f1.x, f1.y, f1.z, f1.w};
    bf16x8 h, l;
    #pragma unroll
    for (int j = 0; j < 8; ++j) {
        __bf16 hj = (__bf16)f[j];
        h[j] = hj;
        l[j] = (__bf16)(f[j] - (float)hj);
    }
    *hi = h;
    *lo = l;
}

__global__ __launch_bounds__(SOM_TPB, 4)
void som_dist_kernel(const float* __restrict__ x,
                     const float* __restrict__ w,
                     float* __restrict__ out) {
    __shared__ float x2s[BLK_BQ];   // ||x_b||^2 for this block's 32 b-rows
    __shared__ float wn2s[BLK_N];   // ||w_n||^2 for this block's 64 n-cols

    const int tid = threadIdx.x;
    const int nb0 = blockIdx.x * BLK_N;   // first n-col of block
    const int bq  = blockIdx.y * BLK_BQ;  // first b-row of block

    // ---- pre-pass: exact fp32 norms -> LDS ----
    if (tid < BLK_BQ) {
        const float4* xr = (const float4*)(x + (size_t)(bq + tid) * SOM_D);
        float s = 0.f;
        #pragma unroll
        for (int i = 0; i < 16; ++i) {
            float4 v = xr[i];
            s += v.x * v.x + v.y * v.y + v.z * v.z + v.w * v.w;
        }
        x2s[tid] = s;
    } else if (tid < BLK_BQ + BLK_N) {
        const int j = tid - BLK_BQ;
        const float4* wr = (const float4*)(w + (size_t)(nb0 + j) * SOM_D);
        float s = 0.f;
        #pragma unroll
        for (int i = 0; i < 16; ++i) {
            float4 v = wr[i];
            s += v.x * v.x + v.y * v.y + v.z * v.z + v.w * v.w;
        }
        wn2s[j] = s;
    }
    __syncthreads();

    // ---- fragment indices ----
    const int wv = tid >> 6;      // wave 0..3
    const int l  = tid & 63;      // lane
    const int lr = l & 15;        // row (A) / col (B) within fragment
    const int lg = l >> 4;        // k-group 0..3
    const int nc = nb0 + wv * 16; // this wave's n-col base

    // ---- B fragments (w), ksteps 0 and 1 ----
    const float* wrow = w + (size_t)(nc + lr) * SOM_D + lg * 8;
    float4 wf0 = *(const float4*)(wrow + 0);
    float4 wf1 = *(const float4*)(wrow + 4);
    float4 wf2 = *(const float4*)(wrow + 32);
    float4 wf3 = *(const float4*)(wrow + 36);
    bf16x8 bh0, bl0, bh1, bl1;
    split8(wf0, wf1, &bh0, &bl0);
    split8(wf2, wf3, &bh1, &bl1);

    const float wn2v = wn2s[wv * 16 + lr];   // this lane's column norm

    // ---- 2 b-subtiles of 16 rows each ----
    #pragma unroll
    for (int sub = 0; sub < 2; ++sub) {
        const int br = bq + sub * 16;
        const float* xrow = x + (size_t)(br + lr) * SOM_D + lg * 8;
        float4 xf0 = *(const float4*)(xrow + 0);
        float4 xf1 = *(const float4*)(xrow + 4);
        float4 xf2 = *(const float4*)(xrow + 32);
        float4 xf3 = *(const float4*)(xrow + 36);
        bf16x8 ah0, al0, ah1, al1;
        split8(xf0, xf1, &ah0, &al0);
        split8(xf2, xf3, &ah1, &al1);

        f32x4 acc = {0.f, 0.f, 0.f, 0.f};
        acc = __builtin_amdgcn_mfma_f32_16x16x32_bf16(ah0, bh0, acc, 0, 0, 0);
        acc = __builtin_amdgcn_mfma_f32_16x16x32_bf16(al0, bh0, acc, 0, 0, 0);
        acc = __builtin_amdgcn_mfma_f32_16x16x32_bf16(ah0, bl0, acc, 0, 0, 0);
        acc = __builtin_amdgcn_mfma_f32_16x16x32_bf16(ah1, bh1, acc, 0, 0, 0);
        acc = __builtin_amdgcn_mfma_f32_16x16x32_bf16(al1, bh1, acc, 0, 0, 0);
        acc = __builtin_amdgcn_mfma_f32_16x16x32_bf16(ah1, bl1, acc, 0, 0, 0);

        // D: row = lg*4 + i, col = lr
        const float4 x2v = *(const float4*)&x2s[sub * 16 + lg * 4];
        const float xx[4] = {x2v.x, x2v.y, x2v.z, x2v.w};
        #pragma unroll
        for (int i = 0; i < 4; ++i) {
            const int row = br + lg * 4 + i;
            out[(size_t)row * SOM_N + nc + lr] =
                __builtin_fmaf(-2.f, acc[i], wn2v + xx[i]);
        }
    }
}

extern "C" void kernel_launch(void* const* d_in, const int* in_sizes, int n_in,
                              void* d_out, int out_size, void* d_ws, size_t ws_size,
                              hipStream_t stream) {
    const float* x = (const float*)d_in[0];   // (128, 64)
    const float* w = (const float*)d_in[1];   // (128, 128, 64)
    float* out = (float*)d_out;               // (128, 128, 128)

    dim3 grid(SOM_N / BLK_N, SOM_B / BLK_BQ);   // (256, 4)
    dim3 block(SOM_TPB);
    som_dist_kernel<<<grid, block, 0, stream>>>(x, w, out);
}